// Round 8
// baseline (483.598 us; speedup 1.0000x reference)
//
#include <hip/hip_runtime.h>
#include <math.h>

#define N_NODES 100000
#define N_EDGES 600000
#define N_GRAPHS 512
#define D 128

typedef unsigned short u16;
typedef __attribute__((ext_vector_type(8))) short short8;
typedef __attribute__((ext_vector_type(4))) float f32x4;
typedef __attribute__((ext_vector_type(4))) unsigned int u32x4;

__device__ __forceinline__ u16 f2bf(float f) {
    unsigned int u = __float_as_uint(f);
    u += 0x7FFFu + ((u >> 16) & 1u);
    return (u16)(u >> 16);
}
__device__ __forceinline__ float bf2f(u16 h) {
    return __uint_as_float(((unsigned int)h) << 16);
}
// packed element: hi bf16 in top 16 bits, lo bf16 in low 16 bits
__device__ __forceinline__ unsigned int packsplit(float v) {
    unsigned int u = __float_as_uint(v);
    unsigned int hi = (u + (0x7FFFu + ((u >> 16) & 1u))) & 0xffff0000u;
    float lo = v - __uint_as_float(hi);
    unsigned int ul = __float_as_uint(lo);
    unsigned int l16 = (ul + (0x7FFFu + ((ul >> 16) & 1u))) >> 16;
    return hi | l16;
}
__device__ __forceinline__ float hi_f(unsigned int w) { return __uint_as_float(w & 0xffff0000u); }
__device__ __forceinline__ float lo_f(unsigned int w) { return __uint_as_float(w << 16); }
__device__ __forceinline__ float unpack_sum(unsigned int w) { return hi_f(w) + lo_f(w); }
// fp32 -> (hi bf16 bits, lo bf16 bits) in low 16 of each
__device__ __forceinline__ void split2(float f, unsigned int& h16, unsigned int& l16) {
    unsigned int u = __float_as_uint(f);
    unsigned int hb = (u + (0x7FFFu + ((u >> 16) & 1u))) & 0xffff0000u;
    float lo = f - __uint_as_float(hb);
    unsigned int ul = __float_as_uint(lo);
    h16 = hb >> 16;
    l16 = (ul + (0x7FFFu + ((ul >> 16) & 1u))) >> 16;
}

// ---------------- zero helper ----------------
__global__ __launch_bounds__(256) void zero_i_kernel(int* __restrict__ p, int n) {
    int i = blockIdx.x * 256 + threadIdx.x;
    if (i < n) p[i] = 0;
}

// ---------------- CSR build ----------------
__global__ __launch_bounds__(256) void hist_kernel(const int* __restrict__ dst,
                                                   int* __restrict__ deg) {
    int e = blockIdx.x * 256 + threadIdx.x;
    if (e < N_EDGES) atomicAdd(&deg[dst[e]], 1);
}

#define SCAN_BS 1024
__global__ __launch_bounds__(1024) void scan1_kernel(const int* __restrict__ deg,
                                                     int* __restrict__ excl,
                                                     int* __restrict__ blocksum) {
    __shared__ int buf[2][SCAN_BS];
    const int t = threadIdx.x;
    const int gid = blockIdx.x * SCAN_BS + t;
    int v = (gid < N_NODES) ? deg[gid] : 0;
    buf[0][t] = v;
    __syncthreads();
    int pi = 0;
    for (int off = 1; off < SCAN_BS; off <<= 1) {
        int val = buf[pi][t];
        if (t >= off) val += buf[pi][t - off];
        buf[pi ^ 1][t] = val;
        pi ^= 1;
        __syncthreads();
    }
    int incl = buf[pi][t];
    if (gid < N_NODES) excl[gid] = incl - v;
    if (t == SCAN_BS - 1) blocksum[blockIdx.x] = incl;
}

// parallel exclusive scan of block totals (<=128 elements), one block
__global__ __launch_bounds__(128) void scan2_kernel(int* __restrict__ blocksum, int n) {
    __shared__ int buf[2][128];
    const int t = threadIdx.x;
    int v = (t < n) ? blocksum[t] : 0;
    buf[0][t] = v;
    __syncthreads();
    int pi = 0;
    for (int off = 1; off < 128; off <<= 1) {
        int val = buf[pi][t];
        if (t >= off) val += buf[pi][t - off];
        buf[pi ^ 1][t] = val;
        pi ^= 1;
        __syncthreads();
    }
    if (t < n) blocksum[t] = buf[pi][t] - v;
}

__global__ __launch_bounds__(256) void scan3_kernel(const int* __restrict__ excl,
                                                    const int* __restrict__ blocksum,
                                                    int* __restrict__ rowptr) {
    int i = blockIdx.x * 256 + threadIdx.x;
    if (i < N_NODES) rowptr[i] = excl[i] + blocksum[i / SCAN_BS];
    if (i == 0) rowptr[N_NODES] = N_EDGES;
}

__global__ __launch_bounds__(256) void fill_kernel(const int* __restrict__ src,
                                                   const int* __restrict__ dst,
                                                   const int* __restrict__ rowptr,
                                                   int* __restrict__ fill,
                                                   int* __restrict__ csr_src) {
    int e = blockIdx.x * 256 + threadIdx.x;
    if (e < N_EDGES) {
        int d = dst[e];
        int pos = rowptr[d] + atomicAdd(&fill[d], 1);
        csr_src[pos] = src[e];
    }
}

// ---------------- pack W' = [Wl ; Wr] (256x128) into MFMA B-fragment layout ----------------
// one launch, 3 layers x 64 tiles. tile t = nt*8+kt.
// Wp[(t*64+lane)*8+j] = W'[kt*32+(lane>>4)*8+j][nt*16+(lane&15)]
__global__ __launch_bounds__(64) void wprep_kernel(const float* __restrict__ Wl1, const float* __restrict__ Wr1,
                                                   const float* __restrict__ Wl2, const float* __restrict__ Wr2,
                                                   const float* __restrict__ Wl3, const float* __restrict__ Wr3,
                                                   u16* __restrict__ wph, u16* __restrict__ wpl) {
    const int layer = blockIdx.x >> 6;
    const int t = blockIdx.x & 63;
    const int lane = threadIdx.x;
    const float* Wl = (layer == 0) ? Wl1 : (layer == 1) ? Wl2 : Wl3;
    const float* Wr = (layer == 0) ? Wr1 : (layer == 1) ? Wr2 : Wr3;
    const int nt = t >> 3, kt = t & 7;
    const int n = nt * 16 + (lane & 15);
    const int k0 = kt * 32 + (lane >> 4) * 8;
    const size_t base = (size_t)layer * 32768 + (size_t)(t * 64 + lane) * 8;
    #pragma unroll
    for (int j = 0; j < 8; ++j) {
        const int k = k0 + j;
        const float w = (k < 128) ? Wl[k * 128 + n] : Wr[(k - 128) * 128 + n];
        const u16 h = f2bf(w);
        wph[base + j] = h;
        wpl[base + j] = f2bf(w - bf2f(h));
    }
}

// ---------------- aggregation: mean of neighbor rows -> packed Mx ----------------
// one wave per node. Lane layout: half=lane>>5 picks even/odd neighbor row,
// sl=lane&31 covers 4 cols (16 B/lane). Wave processes a row PAIR per step,
// unrolled x2 (4 rows, 2 loads/lane in flight). Halves combined by shfl_xor(32).
// Layer 1 reads x (fp32) directly; later layers read packed Hx.
__global__ __launch_bounds__(256) void agg_kernel(const unsigned int* __restrict__ Hx,
                                                  const float* __restrict__ xf,
                                                  const int* __restrict__ rowptr,
                                                  const int* __restrict__ csr_src,
                                                  unsigned int* __restrict__ Mx) {
    const int lane = threadIdx.x & 63;
    const int node = blockIdx.x * 4 + (threadIdx.x >> 6);
    if (node >= N_NODES) return;
    const int beg = rowptr[node];
    const int end = rowptr[node + 1];
    const int half = lane >> 5;
    const int sl = lane & 31;
    const int co = sl * 4;
    float a0 = 0.f, a1 = 0.f, a2 = 0.f, a3 = 0.f;

    for (int c0 = beg; c0 < end; c0 += 64) {
        const int nv = min(64, end - c0);
        int msrc = (c0 + lane < end) ? csr_src[c0 + lane] : 0;
        for (int j = 0; j < nv; j += 4) {
            #pragma unroll
            for (int u = 0; u < 2; ++u) {
                const int idx = j + 2 * u + half;
                const int s = __shfl(msrc, min(idx, nv - 1));
                if (idx < nv) {
                    if (xf) {
                        const float4 v = *(const float4*)(xf + (size_t)s * D + co);
                        a0 += v.x; a1 += v.y; a2 += v.z; a3 += v.w;
                    } else {
                        const uint4 w = *(const uint4*)(Hx + (size_t)s * D + co);
                        a0 += unpack_sum(w.x); a1 += unpack_sum(w.y);
                        a2 += unpack_sum(w.z); a3 += unpack_sum(w.w);
                    }
                }
            }
        }
    }
    a0 += __shfl_xor(a0, 32);
    a1 += __shfl_xor(a1, 32);
    a2 += __shfl_xor(a2, 32);
    a3 += __shfl_xor(a3, 32);
    if (half == 0) {
        const float inv = 1.0f / (float)max(end - beg, 1);
        uint4 o;
        o.x = packsplit(a0 * inv);
        o.y = packsplit(a1 * inv);
        o.z = packsplit(a2 * inv);
        o.w = packsplit(a3 * inv);
        *(uint4*)(Mx + (size_t)node * D + co) = o;
    }
}

// ---------------- MFMA GEMM: h' = relu([M | H] @ [Wl;Wr] + b) ----------------
// 64 rows/block (4 waves x 16), N=128, K=256, bf16x3 emulation.
// W staged per nt-pair in 32 KB LDS (one global copy per block, 4 waves share).
// Root-A from packed Hx, or from fp32 x (layer 1, split in-register).
// h' written packed in place over Hx (per-wave read-before-write: race-free).
__global__ __launch_bounds__(256, 4) void gemm_kernel(const unsigned int* __restrict__ Mx,
                                                      const unsigned int* Hx,
                                                      const float* __restrict__ xroot,
                                                      const u16* __restrict__ Wph,
                                                      const u16* __restrict__ Wpl,
                                                      const float* __restrict__ bias,
                                                      unsigned int* OHx) {
    __shared__ uint4 ldsW[2048];   // 32 KB
    const int lane = threadIdx.x & 63;
    const int wv = threadIdx.x >> 6;
    const int m0 = blockIdx.x * 64 + wv * 16;
    int rm = m0 + (lane & 15);
    if (rm >= N_NODES) rm = 0;
    const int ko = (lane >> 4) * 8;

    short8 ah[8], al[8];
    // mean half (kt 0..3) from packed Mx
    #pragma unroll
    for (int kt = 0; kt < 4; ++kt) {
        const unsigned int* base = Mx + (size_t)rm * D + kt * 32 + ko;
        const u32x4 p = *(const u32x4*)(base);
        const u32x4 q = *(const u32x4*)(base + 4);
        u32x4 hv, lv;
        hv.x = (p.x >> 16) | (p.y & 0xffff0000u);
        hv.y = (p.z >> 16) | (p.w & 0xffff0000u);
        hv.z = (q.x >> 16) | (q.y & 0xffff0000u);
        hv.w = (q.z >> 16) | (q.w & 0xffff0000u);
        lv.x = (p.x & 0xffffu) | (p.y << 16);
        lv.y = (p.z & 0xffffu) | (p.w << 16);
        lv.z = (q.x & 0xffffu) | (q.y << 16);
        lv.w = (q.z & 0xffffu) | (q.w << 16);
        ah[kt] = __builtin_bit_cast(short8, hv);
        al[kt] = __builtin_bit_cast(short8, lv);
    }
    // root half (kt 4..7): packed Hx, or fp32 x split in-register (layer 1)
    if (xroot) {
        #pragma unroll
        for (int kt = 0; kt < 4; ++kt) {
            const float* bx = xroot + (size_t)rm * D + kt * 32 + ko;
            const f32x4 f0 = *(const f32x4*)(bx);
            const f32x4 f1 = *(const f32x4*)(bx + 4);
            unsigned int hh[8], ll[8];
            split2(f0.x, hh[0], ll[0]); split2(f0.y, hh[1], ll[1]);
            split2(f0.z, hh[2], ll[2]); split2(f0.w, hh[3], ll[3]);
            split2(f1.x, hh[4], ll[4]); split2(f1.y, hh[5], ll[5]);
            split2(f1.z, hh[6], ll[6]); split2(f1.w, hh[7], ll[7]);
            u32x4 hv, lv;
            hv.x = hh[0] | (hh[1] << 16); hv.y = hh[2] | (hh[3] << 16);
            hv.z = hh[4] | (hh[5] << 16); hv.w = hh[6] | (hh[7] << 16);
            lv.x = ll[0] | (ll[1] << 16); lv.y = ll[2] | (ll[3] << 16);
            lv.z = ll[4] | (ll[5] << 16); lv.w = ll[6] | (ll[7] << 16);
            ah[4 + kt] = __builtin_bit_cast(short8, hv);
            al[4 + kt] = __builtin_bit_cast(short8, lv);
        }
    } else {
        #pragma unroll
        for (int kt = 0; kt < 4; ++kt) {
            const unsigned int* base = Hx + (size_t)rm * D + kt * 32 + ko;
            const u32x4 p = *(const u32x4*)(base);
            const u32x4 q = *(const u32x4*)(base + 4);
            u32x4 hv, lv;
            hv.x = (p.x >> 16) | (p.y & 0xffff0000u);
            hv.y = (p.z >> 16) | (p.w & 0xffff0000u);
            hv.z = (q.x >> 16) | (q.y & 0xffff0000u);
            hv.w = (q.z >> 16) | (q.w & 0xffff0000u);
            lv.x = (p.x & 0xffffu) | (p.y << 16);
            lv.y = (p.z & 0xffffu) | (p.w << 16);
            lv.z = (q.x & 0xffffu) | (q.y << 16);
            lv.w = (q.z & 0xffffu) | (q.w << 16);
            ah[4 + kt] = __builtin_bit_cast(short8, hv);
            al[4 + kt] = __builtin_bit_cast(short8, lv);
        }
    }

    const int rowb = m0 + ((lane >> 4) << 2);
    const int cl = lane & 15;
    const int t = threadIdx.x;
    const u16* ldsU = (const u16*)ldsW;

    #pragma unroll
    for (int ntc = 0; ntc < 4; ++ntc) {
        __syncthreads();
        {
            const uint4* gh = (const uint4*)(Wph + (size_t)(2 * ntc) * 4096);
            const uint4* gl = (const uint4*)(Wpl + (size_t)(2 * ntc) * 4096);
            #pragma unroll
            for (int i = 0; i < 4; ++i) {
                ldsW[t + 256 * i]        = gh[t + 256 * i];
                ldsW[1024 + t + 256 * i] = gl[t + 256 * i];
            }
        }
        __syncthreads();

        #pragma unroll
        for (int nt2 = 0; nt2 < 2; ++nt2) {
            f32x4 accP = {0.f, 0.f, 0.f, 0.f};
            f32x4 accQ = {0.f, 0.f, 0.f, 0.f};
            #pragma unroll
            for (int kt = 0; kt < 8; ++kt) {
                const int fo = (nt2 * 8 + kt) * 512 + lane * 8;
                const short8 bh = *(const short8*)(ldsU + fo);
                const short8 bl = *(const short8*)(ldsU + 8192 + fo);
                accP = __builtin_amdgcn_mfma_f32_16x16x32_bf16(ah[kt], bh, accP, 0, 0, 0);
                accQ = __builtin_amdgcn_mfma_f32_16x16x32_bf16(al[kt], bh, accQ, 0, 0, 0);
                accQ = __builtin_amdgcn_mfma_f32_16x16x32_bf16(ah[kt], bl, accQ, 0, 0, 0);
            }
            const int col = (ntc * 2 + nt2) * 16 + cl;
            const float bv = bias[col];
            #pragma unroll
            for (int r = 0; r < 4; ++r) {
                const int row = rowb + r;
                if (row < N_NODES) {
                    const float v = fmaxf(accP[r] + accQ[r] + bv, 0.f);
                    OHx[(size_t)row * D + col] = packsplit(v);
                }
            }
        }
    }
}

// ---------------- fused per-graph sum pooling + readout (batch sorted) ----------------
// block per graph; binary search the node range; no atomics, no pooled buffer.
__global__ __launch_bounds__(128) void pool_final_kernel(const unsigned int* __restrict__ Hx,
                                                         const int* __restrict__ batch,
                                                         const float* __restrict__ Wro,
                                                         const float* __restrict__ bro,
                                                         float* __restrict__ out) {
    const int g = blockIdx.x;
    const int c = threadIdx.x;
    int lo = 0, hi = N_NODES;
    while (lo < hi) { int mid = (lo + hi) >> 1; if (batch[mid] < g) lo = mid + 1; else hi = mid; }
    int lo2 = lo, hi2 = N_NODES;
    while (lo2 < hi2) { int mid = (lo2 + hi2) >> 1; if (batch[mid] < g + 1) lo2 = mid + 1; else hi2 = mid; }

    float acc = 0.0f;
    int node = lo;
    for (; node + 4 <= lo2; node += 4) {
        const unsigned int w0 = Hx[(size_t)(node + 0) * D + c];
        const unsigned int w1 = Hx[(size_t)(node + 1) * D + c];
        const unsigned int w2 = Hx[(size_t)(node + 2) * D + c];
        const unsigned int w3 = Hx[(size_t)(node + 3) * D + c];
        acc += unpack_sum(w0) + unpack_sum(w1) + unpack_sum(w2) + unpack_sum(w3);
    }
    for (; node < lo2; ++node) acc += unpack_sum(Hx[(size_t)node * D + c]);

    float v = acc * Wro[c];
    #pragma unroll
    for (int off = 32; off > 0; off >>= 1) v += __shfl_down(v, off, 64);
    __shared__ float partial[2];
    if ((c & 63) == 0) partial[c >> 6] = v;
    __syncthreads();
    if (c == 0) {
        float s = partial[0] + partial[1] + bro[0];
        out[g] = 1.0f / (1.0f + expf(-s));
    }
}

extern "C" void kernel_launch(void* const* d_in, const int* in_sizes, int n_in,
                              void* d_out, int out_size, void* d_ws, size_t ws_size,
                              hipStream_t stream) {
    const float* x     = (const float*)d_in[0];
    const int*   ei    = (const int*)d_in[1];
    const int*   batch = (const int*)d_in[2];
    const int*   src   = ei;
    const int*   dst   = ei + N_EDGES;
    const float* Wl[3] = {(const float*)d_in[3], (const float*)d_in[6], (const float*)d_in[9]};
    const float* Wr[3] = {(const float*)d_in[4], (const float*)d_in[7], (const float*)d_in[10]};
    const float* bs[3] = {(const float*)d_in[5], (const float*)d_in[8], (const float*)d_in[11]};
    const float* Wro   = (const float*)d_in[12];
    const float* bro   = (const float*)d_in[13];
    float* out = (float*)d_out;

    const size_t ND = (size_t)N_NODES * D;
    char* ws = (char*)d_ws;
    unsigned int* Hx = (unsigned int*)ws;          // ND u32 (packed hi/lo)
    unsigned int* Mx = Hx + ND;                    // ND u32
    u16* Wph = (u16*)(Mx + ND);                    // 3*32768 u16
    u16* Wpl = Wph + 3 * 32768;                    // 3*32768 u16
    int* deg      = (int*)(Wpl + 3 * 32768);       // N (deg, fill adjacent for fused zero)
    int* fill     = deg + N_NODES;                 // N
    int* excl     = fill + N_NODES;                // N
    int* blocksum = excl + N_NODES;                // 128
    int* rowptr   = blocksum + 128;                // N+1
    int* csr_src  = rowptr + N_NODES + 1;          // E

    const int EB      = (N_EDGES + 255) / 256;
    const int NB      = (N_NODES + 255) / 256;
    const int NB2     = (2 * N_NODES + 255) / 256;
    const int SCAN_NB = (N_NODES + SCAN_BS - 1) / SCAN_BS;   // 98
    const int AGG_B   = N_NODES / 4;                         // 25000
    const int GEMM_B  = (N_NODES + 63) / 64;                 // 1563

    // ---- CSR build ----
    zero_i_kernel<<<NB2, 256, 0, stream>>>(deg, 2 * N_NODES);   // deg + fill
    hist_kernel<<<EB, 256, 0, stream>>>(dst, deg);
    scan1_kernel<<<SCAN_NB, SCAN_BS, 0, stream>>>(deg, excl, blocksum);
    scan2_kernel<<<1, 128, 0, stream>>>(blocksum, SCAN_NB);
    scan3_kernel<<<NB, 256, 0, stream>>>(excl, blocksum, rowptr);
    fill_kernel<<<EB, 256, 0, stream>>>(src, dst, rowptr, fill, csr_src);

    // ---- prep: pack weights ----
    wprep_kernel<<<192, 64, 0, stream>>>(Wl[0], Wr[0], Wl[1], Wr[1], Wl[2], Wr[2], Wph, Wpl);

    // ---- 3 layers: aggregate-then-GEMM (layer 1 reads x fp32 directly) ----
    for (int l = 0; l < 3; ++l) {
        const float* xl = (l == 0) ? x : (const float*)nullptr;
        agg_kernel<<<AGG_B, 256, 0, stream>>>(Hx, xl, rowptr, csr_src, Mx);
        gemm_kernel<<<GEMM_B, 256, 0, stream>>>(Mx, Hx, xl,
                                                Wph + l * 32768, Wpl + l * 32768, bs[l],
                                                Hx);
    }

    // ---- fused pooling + readout ----
    pool_final_kernel<<<N_GRAPHS, 128, 0, stream>>>(Hx, batch, Wro, bro, out);
}